// Round 1
// baseline (2139.411 us; speedup 1.0000x reference)
//
#include <hip/hip_runtime.h>
#include <math.h>

#define SS 2048
#define BB 4
#define NHD 8
#define DHD 64

// ---------------------------------------------------------------------------
// Generic fp32 GEMM: C[M,512] = A[M,512] @ W[512,512].  Tile 64x64, 256 thr,
// each thread computes 4x4.  K-step 32.  As stored transposed [k][m].
// ---------------------------------------------------------------------------
__global__ __launch_bounds__(256) void gemm512_kernel(
    const float* __restrict__ A, const float* __restrict__ W,
    float* __restrict__ C) {
  __shared__ float As[32][68];
  __shared__ float Bs[32][68];
  const int m0 = blockIdx.x * 64;
  const int n0 = blockIdx.y * 64;
  const int tid = threadIdx.x;
  const int ty = tid >> 4, tx = tid & 15;
  float acc[4][4] = {};
  for (int k0 = 0; k0 < 512; k0 += 32) {
#pragma unroll
    for (int rep = 0; rep < 2; rep++) {
      int idx = rep * 256 + tid;
      // A tile: 64 rows x 32 cols, transposed store
      int ar = idx >> 3, ac4 = (idx & 7) << 2;
      float4 a = *(const float4*)&A[(size_t)(m0 + ar) * 512 + k0 + ac4];
      As[ac4 + 0][ar] = a.x; As[ac4 + 1][ar] = a.y;
      As[ac4 + 2][ar] = a.z; As[ac4 + 3][ar] = a.w;
      // B tile: 32 rows x 64 cols, direct store
      int br = idx >> 4, bc4 = (idx & 15) << 2;
      *(float4*)&Bs[br][bc4] =
          *(const float4*)&W[(size_t)(k0 + br) * 512 + n0 + bc4];
    }
    __syncthreads();
#pragma unroll
    for (int k = 0; k < 32; k++) {
      float4 av = *(const float4*)&As[k][ty << 2];
      float4 bv = *(const float4*)&Bs[k][tx << 2];
      float am[4] = {av.x, av.y, av.z, av.w};
      float bm[4] = {bv.x, bv.y, bv.z, bv.w};
#pragma unroll
      for (int ii = 0; ii < 4; ii++)
#pragma unroll
        for (int jj = 0; jj < 4; jj++)
          acc[ii][jj] = fmaf(am[ii], bm[jj], acc[ii][jj]);
    }
    __syncthreads();
  }
#pragma unroll
  for (int ii = 0; ii < 4; ii++) {
    float4 o = {acc[ii][0], acc[ii][1], acc[ii][2], acc[ii][3]};
    *(float4*)&C[(size_t)(m0 + (ty << 2) + ii) * 512 + n0 + (tx << 2)] = o;
  }
}

// ---------------------------------------------------------------------------
// Fused Transformer-XL relative attention, flash-style online softmax.
// Grid: (S/32, B*H).  Block: 256 threads = 32 query-groups of 8 lanes.
// Lane d-slice: 8 contiguous dims of D_HEAD=64.
// score[i,j] = ((q_i+u).k_j + (q_i+v).r[S-1+j-i]) / 8   for j <= i.
// O aliases Q (each thread reads its own q before writing same addr).
// ---------------------------------------------------------------------------
__global__ __launch_bounds__(256) void flash_rel_kernel(
    const float* __restrict__ Q, const float* __restrict__ K,
    const float* __restrict__ V, const float* __restrict__ R,
    const float* __restrict__ ubias, const float* __restrict__ vbias,
    float* __restrict__ O) {
  constexpr int BQ = 32, BK = 64;
  __shared__ float Ks[64][64];
  __shared__ float Vs[64][64];
  __shared__ float Rs[95][68];  // stride 68: spreads group rows over banks
  const int i0 = blockIdx.x * BQ;
  const int bh = blockIdx.y;
  const int b = bh >> 3, h = bh & 7;
  const int tid = threadIdx.x;
  const int grp = tid >> 3;   // query within block (0..31)
  const int l8 = tid & 7;     // lane in group
  const int d0 = l8 << 3;     // dim slice start
  const int i = i0 + grp;     // global query row

  float qu[8], qv[8];
  {
    const float* qp = &Q[((size_t)(b * SS + i)) * 512 + h * 64 + d0];
    float4 q0 = *(const float4*)qp;
    float4 q1 = *(const float4*)(qp + 4);
    float tq[8] = {q0.x, q0.y, q0.z, q0.w, q1.x, q1.y, q1.z, q1.w};
#pragma unroll
    for (int e = 0; e < 8; e++) {
      qu[e] = tq[e] + ubias[h * 64 + d0 + e];
      qv[e] = tq[e] + vbias[h * 64 + d0 + e];
    }
  }

  float m = -1e30f, l = 0.f;
  float acc[8] = {};

  for (int j0 = 0; j0 < i0 + BQ; j0 += BK) {
    // ---- stage K and V tiles (64x64 each) ----
#pragma unroll
    for (int rep = 0; rep < 4; rep++) {
      int idx = rep * 256 + tid;
      int row = idx >> 4, c4 = (idx & 15) << 2;
      size_t goff = ((size_t)(b * SS + j0 + row)) * 512 + h * 64 + c4;
      *(float4*)&Ks[row][c4] = *(const float4*)&K[goff];
      *(float4*)&Vs[row][c4] = *(const float4*)&V[goff];
    }
    // ---- stage R diagonal band: rows base..base+94 ----
    const int base = SS - BQ + j0 - i0;  // >= 0 always
    for (int idx = tid; idx < 95 * 16; idx += 256) {
      int row = idx >> 4, c4 = (idx & 15) << 2;
      int g = base + row;
      float4 rv = {0.f, 0.f, 0.f, 0.f};
      if (g < SS) rv = *(const float4*)&R[(size_t)g * 512 + h * 64 + c4];
      *(float4*)&Rs[row][c4] = rv;
    }
    __syncthreads();

    // ---- scores for this key block ----
    float s_reg[8];
#pragma unroll
    for (int j = 0; j < BK; j++) {
      int lr = j + (BQ - 1) - grp;  // local R row = S-1+j_g-i - base
      float4 ka = *(const float4*)&Ks[j][d0];
      float4 kb = *(const float4*)&Ks[j][d0 + 4];
      float4 ra = *(const float4*)&Rs[lr][d0];
      float4 rb = *(const float4*)&Rs[lr][d0 + 4];
      float p = qu[0] * ka.x + qu[1] * ka.y + qu[2] * ka.z + qu[3] * ka.w +
                qu[4] * kb.x + qu[5] * kb.y + qu[6] * kb.z + qu[7] * kb.w +
                qv[0] * ra.x + qv[1] * ra.y + qv[2] * ra.z + qv[3] * ra.w +
                qv[4] * rb.x + qv[5] * rb.y + qv[6] * rb.z + qv[7] * rb.w;
      p += __shfl_xor(p, 1, 64);
      p += __shfl_xor(p, 2, 64);
      p += __shfl_xor(p, 4, 64);
      float sc = (j0 + j > i) ? -1e30f : p * 0.125f;
      if ((j & 7) == l8) s_reg[j >> 3] = sc;  // lane keeps j%8==l8
    }

    // ---- online softmax update ----
    float bmax = s_reg[0];
#pragma unroll
    for (int e = 1; e < 8; e++) bmax = fmaxf(bmax, s_reg[e]);
    bmax = fmaxf(bmax, __shfl_xor(bmax, 1, 64));
    bmax = fmaxf(bmax, __shfl_xor(bmax, 2, 64));
    bmax = fmaxf(bmax, __shfl_xor(bmax, 4, 64));
    float m_new = fmaxf(m, bmax);
    float scale = __expf(m - m_new);
    float p_reg[8], psum = 0.f;
#pragma unroll
    for (int e = 0; e < 8; e++) {
      p_reg[e] = __expf(s_reg[e] - m_new);
      psum += p_reg[e];
    }
    psum += __shfl_xor(psum, 1, 64);
    psum += __shfl_xor(psum, 2, 64);
    psum += __shfl_xor(psum, 4, 64);
    l = l * scale + psum;
    m = m_new;
#pragma unroll
    for (int e = 0; e < 8; e++) acc[e] *= scale;

    // ---- PV accumulation ----
#pragma unroll
    for (int j = 0; j < BK; j++) {
      float p = __shfl(p_reg[j >> 3], (tid & 56) | (j & 7), 64);
      float4 va = *(const float4*)&Vs[j][d0];
      float4 vb4 = *(const float4*)&Vs[j][d0 + 4];
      acc[0] = fmaf(p, va.x, acc[0]);
      acc[1] = fmaf(p, va.y, acc[1]);
      acc[2] = fmaf(p, va.z, acc[2]);
      acc[3] = fmaf(p, va.w, acc[3]);
      acc[4] = fmaf(p, vb4.x, acc[4]);
      acc[5] = fmaf(p, vb4.y, acc[5]);
      acc[6] = fmaf(p, vb4.z, acc[6]);
      acc[7] = fmaf(p, vb4.w, acc[7]);
    }
    __syncthreads();
  }

  float inv = 1.f / l;
  float4 o0 = {acc[0] * inv, acc[1] * inv, acc[2] * inv, acc[3] * inv};
  float4 o1 = {acc[4] * inv, acc[5] * inv, acc[6] * inv, acc[7] * inv};
  float* op = &O[((size_t)(b * SS + i)) * 512 + h * 64 + d0];
  *(float4*)op = o0;
  *(float4*)(op + 4) = o1;
}

// ---------------------------------------------------------------------------
extern "C" void kernel_launch(void* const* d_in, const int* in_sizes, int n_in,
                              void* d_out, int out_size, void* d_ws,
                              size_t ws_size, hipStream_t stream) {
  const float* x   = (const float*)d_in[0];
  const float* pos = (const float*)d_in[1];
  const float* Wq  = (const float*)d_in[2];
  const float* Wk  = (const float*)d_in[3];
  const float* Wv  = (const float*)d_in[4];
  const float* Wr  = (const float*)d_in[5];
  const float* Wo  = (const float*)d_in[6];
  const float* ub  = (const float*)d_in[7];
  const float* vb  = (const float*)d_in[8];
  float* out = (float*)d_out;

  // workspace layout (floats): Q | K | V | R ; attn-out aliases Q (safe:
  // each thread reads its q fragment before overwriting the same address,
  // and no other thread touches it).  Total = 3*16MB + 4MB = 52 MB.
  float* ws = (float*)d_ws;
  const size_t BS = (size_t)BB * SS;  // 8192 rows
  float* Qb = ws;
  float* Kb = Qb + BS * 512;
  float* Vb = Kb + BS * 512;
  float* Rb = Vb + BS * 512;
  float* AO = Qb;  // alias

  dim3 blk(256);
  gemm512_kernel<<<dim3(BS / 64, 8), blk, 0, stream>>>(x, Wq, Qb);
  gemm512_kernel<<<dim3(BS / 64, 8), blk, 0, stream>>>(x, Wk, Kb);
  gemm512_kernel<<<dim3(BS / 64, 8), blk, 0, stream>>>(x, Wv, Vb);
  gemm512_kernel<<<dim3(SS / 64, 8), blk, 0, stream>>>(pos, Wr, Rb);
  flash_rel_kernel<<<dim3(SS / 32, BB * NHD), blk, 0, stream>>>(
      Qb, Kb, Vb, Rb, ub, vb, AO);
  gemm512_kernel<<<dim3(BS / 64, 8), blk, 0, stream>>>(AO, Wo, out);
}

// Round 2
// 791.185 us; speedup vs baseline: 2.7041x; 2.7041x over previous
//
#include <hip/hip_runtime.h>
#include <math.h>

#define SS 2048
#define BB 4
#define NHD 8
#define BH (BB * NHD)

typedef float f32x4 __attribute__((ext_vector_type(4)));
typedef __bf16 bf16x8 __attribute__((ext_vector_type(8)));

__device__ __forceinline__ short f2bf(float x) {
  unsigned u = __float_as_uint(x);
  unsigned r = (u + 0x7fffu + ((u >> 16) & 1u)) >> 16;
  return (short)r;
}

// ---------------------------------------------------------------------------
// fp32 GEMM: C[M,512] = A[M,512] @ W[512,512].  (unchanged baseline)
// ---------------------------------------------------------------------------
__global__ __launch_bounds__(256) void gemm512_kernel(
    const float* __restrict__ A, const float* __restrict__ W,
    float* __restrict__ C) {
  __shared__ float As[32][68];
  __shared__ float Bs[32][68];
  const int m0 = blockIdx.x * 64;
  const int n0 = blockIdx.y * 64;
  const int tid = threadIdx.x;
  const int ty = tid >> 4, tx = tid & 15;
  float acc[4][4] = {};
  for (int k0 = 0; k0 < 512; k0 += 32) {
#pragma unroll
    for (int rep = 0; rep < 2; rep++) {
      int idx = rep * 256 + tid;
      int ar = idx >> 3, ac4 = (idx & 7) << 2;
      float4 a = *(const float4*)&A[(size_t)(m0 + ar) * 512 + k0 + ac4];
      As[ac4 + 0][ar] = a.x; As[ac4 + 1][ar] = a.y;
      As[ac4 + 2][ar] = a.z; As[ac4 + 3][ar] = a.w;
      int br = idx >> 4, bc4 = (idx & 15) << 2;
      *(float4*)&Bs[br][bc4] =
          *(const float4*)&W[(size_t)(k0 + br) * 512 + n0 + bc4];
    }
    __syncthreads();
#pragma unroll
    for (int k = 0; k < 32; k++) {
      float4 av = *(const float4*)&As[k][ty << 2];
      float4 bv = *(const float4*)&Bs[k][tx << 2];
      float am[4] = {av.x, av.y, av.z, av.w};
      float bm[4] = {bv.x, bv.y, bv.z, bv.w};
#pragma unroll
      for (int ii = 0; ii < 4; ii++)
#pragma unroll
        for (int jj = 0; jj < 4; jj++)
          acc[ii][jj] = fmaf(am[ii], bm[jj], acc[ii][jj]);
    }
    __syncthreads();
  }
#pragma unroll
  for (int ii = 0; ii < 4; ii++) {
    float4 o = {acc[ii][0], acc[ii][1], acc[ii][2], acc[ii][3]};
    *(float4*)&C[(size_t)(m0 + (ty << 2) + ii) * 512 + n0 + (tx << 2)] = o;
  }
}

// ---------------------------------------------------------------------------
// Prep: Q fp32 [b,s,h*64+d] -> Qu,Qv bf16 head-major [bh][s][64] with biases.
// ---------------------------------------------------------------------------
__global__ void conv_q_kernel(const float* __restrict__ Qf,
                              const float* __restrict__ ub,
                              const float* __restrict__ vb,
                              short* __restrict__ Qu, short* __restrict__ Qv) {
  int idx = blockIdx.x * blockDim.x + threadIdx.x;
  int o = idx * 4;
  int dd = o & 63;
  int s = (o >> 6) & (SS - 1);
  int bhh = o >> 17;  // /(64*2048)
  int b = bhh >> 3, h = bhh & 7;
  float4 q4 = *(const float4*)(Qf + ((size_t)(b * SS + s)) * 512 + h * 64 + dd);
  float4 u4 = *(const float4*)(ub + h * 64 + dd);
  float4 v4 = *(const float4*)(vb + h * 64 + dd);
  short4 a = make_short4(f2bf(q4.x + u4.x), f2bf(q4.y + u4.y),
                         f2bf(q4.z + u4.z), f2bf(q4.w + u4.w));
  short4 c = make_short4(f2bf(q4.x + v4.x), f2bf(q4.y + v4.y),
                         f2bf(q4.z + v4.z), f2bf(q4.w + v4.w));
  *(short4*)(Qu + o) = a;
  *(short4*)(Qv + o) = c;
}

// K (B=4) or R (B=1, bhh=h): fp32 [b,s,h*64+d] -> bf16 [bh][s][64]
__global__ void conv_cast_kernel(const float* __restrict__ In,
                                 short* __restrict__ Out) {
  int idx = blockIdx.x * blockDim.x + threadIdx.x;
  int o = idx * 4;
  int dd = o & 63;
  int s = (o >> 6) & (SS - 1);
  int bhh = o >> 17;
  int b = bhh >> 3, h = bhh & 7;
  float4 q4 = *(const float4*)(In + ((size_t)(b * SS + s)) * 512 + h * 64 + dd);
  short4 a = make_short4(f2bf(q4.x), f2bf(q4.y), f2bf(q4.z), f2bf(q4.w));
  *(short4*)(Out + o) = a;
}

// V fp32 [b,s,h*64+d] -> Vt bf16 [bh][d][s]  (transpose per 64x64 tile)
__global__ __launch_bounds__(256) void conv_vt_kernel(
    const float* __restrict__ Vf, short* __restrict__ Vt) {
  __shared__ float t[64][65];
  const int s0 = blockIdx.x * 64;
  const int bh = blockIdx.y;
  const int b = bh >> 3, h = bh & 7;
  const int tid = threadIdx.x;
#pragma unroll
  for (int rep = 0; rep < 4; rep++) {
    int idx = rep * 256 + tid;
    int r = idx >> 4, c4 = (idx & 15) << 2;
    float4 vv = *(const float4*)(Vf + ((size_t)(b * SS + s0 + r)) * 512 + h * 64 + c4);
    t[r][c4 + 0] = vv.x; t[r][c4 + 1] = vv.y;
    t[r][c4 + 2] = vv.z; t[r][c4 + 3] = vv.w;
  }
  __syncthreads();
#pragma unroll
  for (int rep = 0; rep < 4; rep++) {
    int idx = rep * 256 + tid;
    int d = idx >> 4, s4 = (idx & 15) << 2;
    short4 pv = make_short4(f2bf(t[s4 + 0][d]), f2bf(t[s4 + 1][d]),
                            f2bf(t[s4 + 2][d]), f2bf(t[s4 + 3][d]));
    *(short4*)(Vt + ((size_t)bh * 64 + d) * SS + s0 + s4) = pv;
  }
}

// ---------------------------------------------------------------------------
// MFMA flash attention with Transformer-XL relative shift.
// Block = 4 waves; each wave owns 16 queries; BK=64 keys per chunk.
// Scores S^T[k,q] = mfma(K_row_frags, Qu_frags); BD via banded QR^T GEMM
// staged in per-wave LDS, gathered with the t = k+15-q diagonal shift.
// No __syncthreads needed (all LDS is per-wave).
// ---------------------------------------------------------------------------
__global__ __launch_bounds__(256, 2) void flash_mfma_kernel(
    const short* __restrict__ Qu_, const short* __restrict__ Qv_,
    const short* __restrict__ Kb_, const short* __restrict__ Vt_,
    const short* __restrict__ Rb_, float* __restrict__ O) {
  __shared__ __align__(16) float QRl[4][80 * 18];  // per-wave, stride 18
  __shared__ __align__(16) short Pl[4][16 * 72];   // per-wave, stride 72

  const int qi = (SS / 64 - 1) - blockIdx.x;  // big blocks first
  const int i0 = qi * 64;
  const int bh = blockIdx.y;
  const int h = bh & 7;
  const int tid = threadIdx.x;
  const int wq = tid >> 6;
  const int lane = tid & 63;
  const int q = lane & 15;   // score col = query; PV col = d_local
  const int g = lane >> 4;   // lane group
  const int dsl = g * 8;     // 8-elem slice base

  float* qrw = QRl[wq];
  short* pw = Pl[wq];

  // hoisted Q fragments (B operand): lane holds col q, k-dims dsl(+32c)
  const size_t qoff = ((size_t)bh * SS + (i0 + wq * 16 + q)) * 64;
  bf16x8 quF[2], qvF[2];
  quF[0] = *(const bf16x8*)(Qu_ + qoff + dsl);
  quF[1] = *(const bf16x8*)(Qu_ + qoff + dsl + 32);
  qvF[0] = *(const bf16x8*)(Qv_ + qoff + dsl);
  qvF[1] = *(const bf16x8*)(Qv_ + qoff + dsl + 32);

  const int i_my = i0 + wq * 16 + q;

  float m = -1e30f, l = 0.f;
  f32x4 o[4] = {};  // o[dsub][r]: element r -> query 4g+r, d = dsub*16+q

  for (int j0 = 0; j0 <= i0; j0 += 64) {
    f32x4 accS[4] = {};
    f32x4 accR[5] = {};
    const size_t kbase = ((size_t)bh * SS + j0) * 64;
    const int rb0 = SS - 16 + j0 - i0 - 16 * wq;
    const size_t rbase = (size_t)h * SS * 64;
#pragma unroll
    for (int c = 0; c < 2; c++) {
      const int dof = dsl + 32 * c;
#pragma unroll
      for (int ks = 0; ks < 4; ks++) {
        bf16x8 kf = *(const bf16x8*)(Kb_ + kbase + (size_t)(ks * 16 + q) * 64 + dof);
        accS[ks] = __builtin_amdgcn_mfma_f32_16x16x32_bf16(kf, quF[c], accS[ks], 0, 0, 0);
      }
#pragma unroll
      for (int st = 0; st < 5; st++) {
        int rrow = rb0 + st * 16 + q;
        rrow = rrow < SS ? rrow : SS - 1;  // clamp (masked region only)
        bf16x8 rf = *(const bf16x8*)(Rb_ + rbase + (size_t)rrow * 64 + dof);
        accR[st] = __builtin_amdgcn_mfma_f32_16x16x32_bf16(rf, qvF[c], accR[st], 0, 0, 0);
      }
    }

    // stage QR^T band into per-wave LDS: row t_wave = k+15-q, col q
#pragma unroll
    for (int st = 0; st < 5; st++) {
#pragma unroll
      for (int r = 0; r < 4; r++) {
        int tw = st * 16 + g * 4 + r;
        qrw[tw * 18 + q] = accR[st][r];
      }
    }

    // assemble scores: AC + shifted-BD, scale, causal mask
    float sreg[4][4];
#pragma unroll
    for (int ks = 0; ks < 4; ks++) {
#pragma unroll
      for (int r = 0; r < 4; r++) {
        int krow = ks * 16 + g * 4 + r;
        float qr = qrw[(krow + 15 - q) * 18 + q];
        float sc = (accS[ks][r] + qr) * 0.125f;
        sreg[ks][r] = (j0 + krow <= i_my) ? sc : -1e30f;
      }
    }

    // online softmax per q-column (4 lanes {q,q+16,q+32,q+48})
    float bmax = sreg[0][0];
#pragma unroll
    for (int ks = 0; ks < 4; ks++)
#pragma unroll
      for (int r = 0; r < 4; r++) bmax = fmaxf(bmax, sreg[ks][r]);
    bmax = fmaxf(bmax, __shfl_xor(bmax, 16, 64));
    bmax = fmaxf(bmax, __shfl_xor(bmax, 32, 64));
    float mnew = fmaxf(m, bmax);
    float scale = __expf(m - mnew);
    float psum = 0.f;
    short4 pk[4];
#pragma unroll
    for (int ks = 0; ks < 4; ks++) {
      float p0 = __expf(sreg[ks][0] - mnew);
      float p1 = __expf(sreg[ks][1] - mnew);
      float p2 = __expf(sreg[ks][2] - mnew);
      float p3 = __expf(sreg[ks][3] - mnew);
      psum += (p0 + p1) + (p2 + p3);
      pk[ks] = make_short4(f2bf(p0), f2bf(p1), f2bf(p2), f2bf(p3));
    }
    psum += __shfl_xor(psum, 16, 64);
    psum += __shfl_xor(psum, 32, 64);
    l = l * scale + psum;
    m = mnew;

    // P -> LDS [q][k] (bf16, stride 72)
#pragma unroll
    for (int ks = 0; ks < 4; ks++)
      *(short4*)(pw + q * 72 + ks * 16 + g * 4) = pk[ks];

    // rescale output accumulators (element r belongs to query 4g+r)
#pragma unroll
    for (int r = 0; r < 4; r++) {
      float sc_r = __shfl(scale, g * 4 + r, 64);
      o[0][r] *= sc_r; o[1][r] *= sc_r; o[2][r] *= sc_r; o[3][r] *= sc_r;
    }

    // PV: A = P[q,k] from LDS; B = V^T slices from global
    bf16x8 pf[2];
    pf[0] = *(const bf16x8*)(pw + q * 72 + dsl);
    pf[1] = *(const bf16x8*)(pw + q * 72 + dsl + 32);
    const size_t vtb = ((size_t)bh * 64) * SS + j0;
#pragma unroll
    for (int ds = 0; ds < 4; ds++) {
#pragma unroll
      for (int c = 0; c < 2; c++) {
        bf16x8 vf = *(const bf16x8*)(Vt_ + vtb + (size_t)(ds * 16 + q) * SS + dsl + 32 * c);
        o[ds] = __builtin_amdgcn_mfma_f32_16x16x32_bf16(pf[c], vf, o[ds], 0, 0, 0);
      }
    }
  }

  // write out: O[b, i, h*64 + d] fp32
  const int b = bh >> 3;
  float linv = 1.f / l;
#pragma unroll
  for (int r = 0; r < 4; r++) {
    float li = __shfl(linv, g * 4 + r, 64);
    int irow = i0 + wq * 16 + g * 4 + r;
    float* op = O + ((size_t)(b * SS + irow)) * 512 + h * 64 + q;
#pragma unroll
    for (int ds = 0; ds < 4; ds++) op[ds * 16] = o[ds][r] * li;
  }
}

// ---------------------------------------------------------------------------
extern "C" void kernel_launch(void* const* d_in, const int* in_sizes, int n_in,
                              void* d_out, int out_size, void* d_ws,
                              size_t ws_size, hipStream_t stream) {
  const float* x   = (const float*)d_in[0];
  const float* pos = (const float*)d_in[1];
  const float* Wq  = (const float*)d_in[2];
  const float* Wk  = (const float*)d_in[3];
  const float* Wv  = (const float*)d_in[4];
  const float* Wr  = (const float*)d_in[5];
  const float* Wo  = (const float*)d_in[6];
  const float* ub  = (const float*)d_in[7];
  const float* vb  = (const float*)d_in[8];
  float* out = (float*)d_out;

  const size_t BS = (size_t)BB * SS;            // 8192
  const size_t NQ = BS * 512;                   // 4.19M elems
  const size_t NR = (size_t)SS * 512;           // 1.05M elems

  // fp32 region: Qf | Kf | Vf | Rf   (54.5 MB)
  float* Qf = (float*)d_ws;
  float* Kf = Qf + NQ;
  float* Vf = Kf + NQ;
  float* Rf = Vf + NQ;
  // bf16 region appended (35.6 MB): Qu | Qv | Kb | Vt | Rb
  short* Qu = (short*)(Rf + NR);
  short* Qv = Qu + NQ;
  short* Kb = Qv + NQ;
  short* Vt = Kb + NQ;
  short* Rb = Vt + NQ;
  float* AO = Qf;  // flash output aliases Qf (dead after conv_q)

  dim3 blk(256);
  gemm512_kernel<<<dim3(BS / 64, 8), blk, 0, stream>>>(x, Wq, Qf);
  gemm512_kernel<<<dim3(BS / 64, 8), blk, 0, stream>>>(x, Wk, Kf);
  gemm512_kernel<<<dim3(BS / 64, 8), blk, 0, stream>>>(x, Wv, Vf);
  gemm512_kernel<<<dim3(SS / 64, 8), blk, 0, stream>>>(pos, Wr, Rf);

  conv_q_kernel<<<dim3(NQ / 4 / 256), blk, 0, stream>>>(Qf, ub, vb, Qu, Qv);
  conv_cast_kernel<<<dim3(NQ / 4 / 256), blk, 0, stream>>>(Kf, Kb);
  conv_cast_kernel<<<dim3(NR / 4 / 256), blk, 0, stream>>>(Rf, Rb);
  conv_vt_kernel<<<dim3(SS / 64, BH), blk, 0, stream>>>(Vf, Vt);

  flash_mfma_kernel<<<dim3(SS / 64, BH), blk, 0, stream>>>(Qu, Qv, Kb, Vt, Rb, AO);

  gemm512_kernel<<<dim3(BS / 64, 8), blk, 0, stream>>>(AO, Wo, out);
}

// Round 3
// 336.572 us; speedup vs baseline: 6.3565x; 2.3507x over previous
//
#include <hip/hip_runtime.h>
#include <math.h>

#define SS 2048
#define BB 4
#define NHD 8
#define BH (BB * NHD)

typedef float f32x4 __attribute__((ext_vector_type(4)));
typedef __bf16 bf16x8 __attribute__((ext_vector_type(8)));

__device__ __forceinline__ short f2bf(float x) {
  unsigned u = __float_as_uint(x);
  unsigned r = (u + 0x7fffu + ((u >> 16) & 1u)) >> 16;
  return (short)r;
}

__device__ __forceinline__ void gld16(const void* g, void* l) {
  __builtin_amdgcn_global_load_lds(
      (const __attribute__((address_space(1))) unsigned int*)g,
      (__attribute__((address_space(3))) unsigned int*)l, 16, 0, 0);
}

// ---------------------------------------------------------------------------
// cast fp32 -> bf16, 4 elems/thread
// ---------------------------------------------------------------------------
__global__ void cast_bf16(const float* __restrict__ in, short* __restrict__ out) {
  int i = blockIdx.x * blockDim.x + threadIdx.x;
  float4 v = ((const float4*)in)[i];
  ((short4*)out)[i] = make_short4(f2bf(v.x), f2bf(v.y), f2bf(v.z), f2bf(v.w));
}

// ---------------------------------------------------------------------------
// W [512k][512n] fp32 -> Wt [n][k] bf16, 5 matrices via blockIdx.z
// ---------------------------------------------------------------------------
__global__ __launch_bounds__(256) void castT_w(
    const float* __restrict__ W0, const float* __restrict__ W1,
    const float* __restrict__ W2, const float* __restrict__ W3,
    const float* __restrict__ W4, short* __restrict__ T0, short* __restrict__ T1,
    short* __restrict__ T2, short* __restrict__ T3, short* __restrict__ T4) {
  __shared__ float t[64][65];
  const float* W;
  short* T;
  switch (blockIdx.z) {
    case 0: W = W0; T = T0; break;
    case 1: W = W1; T = T1; break;
    case 2: W = W2; T = T2; break;
    case 3: W = W3; T = T3; break;
    default: W = W4; T = T4; break;
  }
  const int k0 = blockIdx.x * 64, n0 = blockIdx.y * 64;
  const int tid = threadIdx.x;
#pragma unroll
  for (int rep = 0; rep < 4; rep++) {
    int idx = rep * 256 + tid;
    int r = idx >> 4, c4 = (idx & 15) << 2;
    float4 v = *(const float4*)&W[(size_t)(k0 + r) * 512 + n0 + c4];
    t[r][c4] = v.x; t[r][c4 + 1] = v.y; t[r][c4 + 2] = v.z; t[r][c4 + 3] = v.w;
  }
  __syncthreads();
#pragma unroll
  for (int rep = 0; rep < 4; rep++) {
    int idx = rep * 256 + tid;
    int n = idx >> 4, k4 = (idx & 15) << 2;
    short4 s = make_short4(f2bf(t[k4][n]), f2bf(t[k4 + 1][n]),
                           f2bf(t[k4 + 2][n]), f2bf(t[k4 + 3][n]));
    *(short4*)&T[(size_t)(n0 + n) * 512 + k0 + k4] = s;
  }
}

// ---------------------------------------------------------------------------
// Vh bf16 [bh][s][64] -> Vt bf16 [bh][d][s]
// ---------------------------------------------------------------------------
__global__ __launch_bounds__(256) void conv_vt(const short* __restrict__ Vh,
                                               short* __restrict__ Vt) {
  __shared__ short t[64][72];
  const int s0 = blockIdx.x * 64, bh = blockIdx.y, tid = threadIdx.x;
#pragma unroll
  for (int rep = 0; rep < 4; rep++) {
    int idx = rep * 256 + tid;
    int r = idx >> 4, c4 = (idx & 15) << 2;
    *(short4*)&t[r][c4] = *(const short4*)&Vh[((size_t)bh * SS + s0 + r) * 64 + c4];
  }
  __syncthreads();
#pragma unroll
  for (int rep = 0; rep < 4; rep++) {
    int idx = rep * 256 + tid;
    int d = idx >> 4, s4 = (idx & 15) << 2;
    short4 o = make_short4(t[s4][d], t[s4 + 1][d], t[s4 + 2][d], t[s4 + 3][d]);
    *(short4*)&Vt[((size_t)bh * 64 + d) * SS + s0 + s4] = o;
  }
}

// ---------------------------------------------------------------------------
// bf16 MFMA GEMM: C[M,512] = A[M,512] @ Bt[n][k]^T.  Tile 128x128, BK=64,
// 8 waves (2x4), double-buffered global_load_lds (16B) with XOR swizzle.
// EPI 0: fp32 out.  EPI 1: Qu/Qv bf16 head-major + biases.  EPI 2: bf16 HM.
// ---------------------------------------------------------------------------
template <int EPI>
__global__ __launch_bounds__(512) void mfma_gemm(
    const short* __restrict__ A, const short* __restrict__ Bt, int M,
    short* __restrict__ o0, short* __restrict__ o1,
    const float* __restrict__ bias0, const float* __restrict__ bias1,
    float* __restrict__ of) {
  __shared__ short lds[2][2][128 * 64];
  const int m0 = blockIdx.x * 128;
  const int n0 = blockIdx.y * 128;
  const int tid = threadIdx.x;
  const int lane = tid & 63;
  const int w = tid >> 6;
  const int wr = w >> 2, wc = w & 3;
  const int g = lane >> 4, li = lane & 15;

  f32x4 acc[4][2] = {};

  auto stage = [&](int buf, int k0) {
#pragma unroll
    for (int i = 0; i < 2; i++) {
      int p = (i * 512 + tid) * 16;   // byte offset in 16KB tile (linear LDS)
      int q = p ^ ((p >> 3) & 0x70);  // swizzled source byte (involution)
      int row = q >> 7, col = (q & 127) >> 1;
      gld16(A + (size_t)(m0 + row) * 512 + k0 + col, (char*)&lds[buf][0][0] + p);
      gld16(Bt + (size_t)(n0 + row) * 512 + k0 + col, (char*)&lds[buf][1][0] + p);
    }
  };

  stage(0, 0);
  __syncthreads();
  int buf = 0;
  for (int t = 0; t < 8; t++) {
    if (t < 7) stage(buf ^ 1, (t + 1) * 64);
    const char* As = (const char*)&lds[buf][0][0];
    const char* Bs = (const char*)&lds[buf][1][0];
    bf16x8 af[4][2], bfr[2][2];
#pragma unroll
    for (int ks = 0; ks < 2; ks++) {
      const int cb = g * 16 + ks * 64;
#pragma unroll
      for (int mi = 0; mi < 4; mi++) {
        int row = wr * 64 + mi * 16 + li;
        af[mi][ks] = *(const bf16x8*)(As + row * 128 + (cb ^ ((row & 7) << 4)));
      }
#pragma unroll
      for (int ni = 0; ni < 2; ni++) {
        int row = wc * 32 + ni * 16 + li;
        bfr[ni][ks] = *(const bf16x8*)(Bs + row * 128 + (cb ^ ((row & 7) << 4)));
      }
    }
#pragma unroll
    for (int ks = 0; ks < 2; ks++)
#pragma unroll
      for (int mi = 0; mi < 4; mi++)
#pragma unroll
        for (int ni = 0; ni < 2; ni++)
          acc[mi][ni] = __builtin_amdgcn_mfma_f32_16x16x32_bf16(
              af[mi][ks], bfr[ni][ks], acc[mi][ni], 0, 0, 0);
    __syncthreads();
    buf ^= 1;
  }

#pragma unroll
  for (int mi = 0; mi < 4; mi++) {
#pragma unroll
    for (int ni = 0; ni < 2; ni++) {
      const int n_g = n0 + wc * 32 + ni * 16 + li;
      const int m_b = m0 + wr * 64 + mi * 16 + g * 4;
      if (EPI == 0) {
#pragma unroll
        for (int r = 0; r < 4; r++)
          of[(size_t)(m_b + r) * 512 + n_g] = acc[mi][ni][r];
      } else if (EPI == 1) {
        const float b0 = bias0[n_g], b1 = bias1[n_g];
        const int h = n_g >> 6, d = n_g & 63;
#pragma unroll
        for (int r = 0; r < 4; r++) {
          int m_g = m_b + r;
          size_t ad = ((size_t)((m_g >> 11) * NHD + h) * SS + (m_g & 2047)) * 64 + d;
          o0[ad] = f2bf(acc[mi][ni][r] + b0);
          o1[ad] = f2bf(acc[mi][ni][r] + b1);
        }
      } else {
        const int h = n_g >> 6, d = n_g & 63;
#pragma unroll
        for (int r = 0; r < 4; r++) {
          int m_g = m_b + r;
          size_t ad = ((size_t)((m_g >> 11) * NHD + h) * SS + (m_g & 2047)) * 64 + d;
          o0[ad] = f2bf(acc[mi][ni][r]);
        }
      }
    }
  }
}

// ---------------------------------------------------------------------------
// MFMA flash attention, Transformer-XL relative shift.  8 waves = two 4-wave
// groups; group 0 handles query-tile (31-bx), group 1 handles bx -> uniform
// 132 wave-chunks per block.  Per-wave LDS only (no barriers).
// ---------------------------------------------------------------------------
__global__ __launch_bounds__(512, 4) void flash_mfma_kernel(
    const short* __restrict__ Qu_, const short* __restrict__ Qv_,
    const short* __restrict__ Kb_, const short* __restrict__ Vt_,
    const short* __restrict__ Rb_, short* __restrict__ AOb) {
  __shared__ __align__(16) float QRl[8][80 * 18];
  __shared__ __align__(16) short Pl[8][16 * 72];

  const int bx = blockIdx.x;  // 0..15
  const int bh = blockIdx.y;
  const int h = bh & 7;
  const int tid = threadIdx.x;
  const int w = tid >> 6;
  const int wq = w & 3;
  const int qi = (w < 4) ? (31 - bx) : bx;
  const int i0 = qi * 64;
  const int lane = tid & 63;
  const int q = lane & 15;
  const int g = lane >> 4;
  const int dsl = g * 8;

  float* qrw = QRl[w];
  short* pw = Pl[w];

  const size_t qoff = ((size_t)bh * SS + (i0 + wq * 16 + q)) * 64;
  bf16x8 quF[2], qvF[2];
  quF[0] = *(const bf16x8*)(Qu_ + qoff + dsl);
  quF[1] = *(const bf16x8*)(Qu_ + qoff + dsl + 32);
  qvF[0] = *(const bf16x8*)(Qv_ + qoff + dsl);
  qvF[1] = *(const bf16x8*)(Qv_ + qoff + dsl + 32);

  const int i_my = i0 + wq * 16 + q;

  float m = -1e30f, l = 0.f;
  f32x4 o[4] = {};

  for (int j0 = 0; j0 <= i0; j0 += 64) {
    // hoist V loads: in flight during AC/BD/softmax
    bf16x8 vf[4][2];
    const size_t vtb = ((size_t)bh * 64) * SS + j0;
#pragma unroll
    for (int ds = 0; ds < 4; ds++)
#pragma unroll
      for (int c = 0; c < 2; c++)
        vf[ds][c] = *(const bf16x8*)(Vt_ + vtb + (size_t)(ds * 16 + q) * SS + dsl + 32 * c);

    f32x4 accS[4] = {};
    f32x4 accR[5] = {};
    const size_t kbase = ((size_t)bh * SS + j0) * 64;
    const int rb0 = SS - 16 + j0 - i0 - 16 * wq;
    const size_t rbase = (size_t)h * SS * 64;
#pragma unroll
    for (int c = 0; c < 2; c++) {
      const int dof = dsl + 32 * c;
#pragma unroll
      for (int ks = 0; ks < 4; ks++) {
        bf16x8 kf = *(const bf16x8*)(Kb_ + kbase + (size_t)(ks * 16 + q) * 64 + dof);
        accS[ks] = __builtin_amdgcn_mfma_f32_16x16x32_bf16(kf, quF[c], accS[ks], 0, 0, 0);
      }
#pragma unroll
      for (int st = 0; st < 5; st++) {
        int rrow = rb0 + st * 16 + q;
        rrow = rrow < SS ? rrow : SS - 1;  // clamp (masked region only)
        bf16x8 rf = *(const bf16x8*)(Rb_ + rbase + (size_t)rrow * 64 + dof);
        accR[st] = __builtin_amdgcn_mfma_f32_16x16x32_bf16(rf, qvF[c], accR[st], 0, 0, 0);
      }
    }

#pragma unroll
    for (int st = 0; st < 5; st++)
#pragma unroll
      for (int r = 0; r < 4; r++)
        qrw[(st * 16 + g * 4 + r) * 18 + q] = accR[st][r];

    float sreg[4][4];
#pragma unroll
    for (int ks = 0; ks < 4; ks++)
#pragma unroll
      for (int r = 0; r < 4; r++) {
        int krow = ks * 16 + g * 4 + r;
        float qr = qrw[(krow + 15 - q) * 18 + q];
        float sc = (accS[ks][r] + qr) * 0.125f;
        sreg[ks][r] = (j0 + krow <= i_my) ? sc : -1e30f;
      }

    float bmax = sreg[0][0];
#pragma unroll
    for (int ks = 0; ks < 4; ks++)
#pragma unroll
      for (int r = 0; r < 4; r++) bmax = fmaxf(bmax, sreg[ks][r]);
    bmax = fmaxf(bmax, __shfl_xor(bmax, 16, 64));
    bmax = fmaxf(bmax, __shfl_xor(bmax, 32, 64));
    float mnew = fmaxf(m, bmax);
    float scale = __expf(m - mnew);
    float psum = 0.f;
    short4 pk[4];
#pragma unroll
    for (int ks = 0; ks < 4; ks++) {
      float p0 = __expf(sreg[ks][0] - mnew);
      float p1 = __expf(sreg[ks][1] - mnew);
      float p2 = __expf(sreg[ks][2] - mnew);
      float p3 = __expf(sreg[ks][3] - mnew);
      psum += (p0 + p1) + (p2 + p3);
      pk[ks] = make_short4(f2bf(p0), f2bf(p1), f2bf(p2), f2bf(p3));
    }
    psum += __shfl_xor(psum, 16, 64);
    psum += __shfl_xor(psum, 32, 64);
    l = l * scale + psum;
    m = mnew;

#pragma unroll
    for (int ks = 0; ks < 4; ks++)
      *(short4*)(pw + q * 72 + ks * 16 + g * 4) = pk[ks];

#pragma unroll
    for (int r = 0; r < 4; r++) {
      float sc_r = __shfl(scale, g * 4 + r, 64);
      o[0][r] *= sc_r; o[1][r] *= sc_r; o[2][r] *= sc_r; o[3][r] *= sc_r;
    }

    bf16x8 pf[2];
    pf[0] = *(const bf16x8*)(pw + q * 72 + dsl);
    pf[1] = *(const bf16x8*)(pw + q * 72 + dsl + 32);
#pragma unroll
    for (int ds = 0; ds < 4; ds++)
#pragma unroll
      for (int c = 0; c < 2; c++)
        o[ds] = __builtin_amdgcn_mfma_f32_16x16x32_bf16(pf[c], vf[ds][c], o[ds], 0, 0, 0);
  }

  const int b = bh >> 3;
  float linv = 1.f / l;
#pragma unroll
  for (int r = 0; r < 4; r++) {
    float li2 = __shfl(linv, g * 4 + r, 64);
    int irow = i0 + wq * 16 + g * 4 + r;
    short* op = AOb + ((size_t)(b * SS + irow)) * 512 + h * 64 + q;
#pragma unroll
    for (int ds = 0; ds < 4; ds++) op[ds * 16] = f2bf(o[ds][r] * li2);
  }
}

// ---------------------------------------------------------------------------
extern "C" void kernel_launch(void* const* d_in, const int* in_sizes, int n_in,
                              void* d_out, int out_size, void* d_ws,
                              size_t ws_size, hipStream_t stream) {
  const float* x   = (const float*)d_in[0];
  const float* pos = (const float*)d_in[1];
  const float* Wq  = (const float*)d_in[2];
  const float* Wk  = (const float*)d_in[3];
  const float* Wv  = (const float*)d_in[4];
  const float* Wr  = (const float*)d_in[5];
  const float* Wo  = (const float*)d_in[6];
  const float* ub  = (const float*)d_in[7];
  const float* vb  = (const float*)d_in[8];
  float* out = (float*)d_out;

  const size_t BS = (size_t)BB * SS;   // 8192
  const size_t NX = BS * 512;          // 4194304
  const size_t NR = (size_t)SS * 512;  // 1048576
  const size_t NW = 512 * 512;

  short* xb  = (short*)d_ws;
  short* pb  = xb + NX;
  short* WtQ = pb + NR;
  short* WtK = WtQ + NW;
  short* WtV = WtK + NW;
  short* WtR = WtV + NW;
  short* WtO = WtR + NW;
  short* Qu  = WtO + NW;
  short* Qv  = Qu + NX;
  short* Kb  = Qv + NX;
  short* Vh  = Kb + NX;
  short* Vt  = Vh + NX;
  short* Rb  = Vt + NX;
  short* AOb = Rb + NR;

  cast_bf16<<<dim3(NX / 1024), 256, 0, stream>>>(x, xb);
  cast_bf16<<<dim3(NR / 1024), 256, 0, stream>>>(pos, pb);
  castT_w<<<dim3(8, 8, 5), 256, 0, stream>>>(Wq, Wk, Wv, Wr, Wo,
                                             WtQ, WtK, WtV, WtR, WtO);

  mfma_gemm<1><<<dim3(64, 4), 512, 0, stream>>>(xb, WtQ, 8192, Qu, Qv, ub, vb, nullptr);
  mfma_gemm<2><<<dim3(64, 4), 512, 0, stream>>>(xb, WtK, 8192, Kb, nullptr, nullptr, nullptr, nullptr);
  mfma_gemm<2><<<dim3(64, 4), 512, 0, stream>>>(xb, WtV, 8192, Vh, nullptr, nullptr, nullptr, nullptr);
  mfma_gemm<2><<<dim3(16, 4), 512, 0, stream>>>(pb, WtR, 2048, Rb, nullptr, nullptr, nullptr, nullptr);
  conv_vt<<<dim3(SS / 64, BH), 256, 0, stream>>>(Vh, Vt);

  flash_mfma_kernel<<<dim3(16, BH), 512, 0, stream>>>(Qu, Qv, Kb, Vt, Rb, AOb);

  mfma_gemm<0><<<dim3(64, 4), 512, 0, stream>>>(AOb, WtO, 8192, nullptr, nullptr, nullptr, nullptr, out);
}